// Round 1
// baseline (1631.694 us; speedup 1.0000x reference)
//
#include <hip/hip_runtime.h>

#define NNODES 100000
#define DIM 128

// Y[r][c] = sum_k act(X[r][k]) * W[k][c] + b[c]
// Block: 256 threads, computes a 16-row x 128-col tile.
// Thread t: col c = t&127, rows rbase..rbase+7 where rbase = (t>>7)*8.
template <bool RELU_IN>
__global__ __launch_bounds__(256) void gemm_bias(const float* __restrict__ X,
                                                 const float* __restrict__ W,
                                                 const float* __restrict__ b,
                                                 float* __restrict__ Y, int n) {
    __shared__ float xs[16][DIM];
    const int row0 = blockIdx.x * 16;
    const int t = threadIdx.x;

    // Stage X tile (16x128 floats) into LDS, coalesced.
    for (int i = t; i < 16 * DIM; i += 256) {
        const int r = i >> 7, k = i & 127;
        const int rr = row0 + r;
        float v = (rr < n) ? X[(size_t)rr * DIM + k] : 0.f;
        if (RELU_IN) v = fmaxf(v, 0.f);
        xs[r][k] = v;
    }
    __syncthreads();

    const int c = t & 127;
    const int rbase = (t >> 7) * 8;
    float acc[8];
    const float bias = b[c];
#pragma unroll
    for (int r = 0; r < 8; ++r) acc[r] = bias;

    for (int k = 0; k < DIM; ++k) {
        const float wv = W[k * DIM + c];  // coalesced across the 128-thread c-group
#pragma unroll
        for (int r = 0; r < 8; ++r) acc[r] += xs[rbase + r][k] * wv;  // LDS broadcast
    }

#pragma unroll
    for (int r = 0; r < 8; ++r) {
        const int rr = row0 + rbase + r;
        if (rr < n) Y[(size_t)rr * DIM + c] = acc[r];
    }
}

// out[rows[e]][f] += vals[e] * X[cols[e]][f], edge-parallel, 128 threads/edge.
__global__ __launch_bounds__(256) void spmm_atomic(const int* __restrict__ rows,
                                                   const int* __restrict__ cols,
                                                   const float* __restrict__ vals,
                                                   const float* __restrict__ X,
                                                   float* __restrict__ out, int nnz) {
    const long long idx = (long long)blockIdx.x * blockDim.x + threadIdx.x;
    const int e = (int)(idx >> 7);
    const int f = (int)(idx & 127);
    if (e >= nnz) return;
    const int r = rows[e];
    const int c = cols[e];
    const float v = vals[e];
    atomicAdd(&out[(size_t)r * DIM + f], v * X[(size_t)c * DIM + f]);
}

extern "C" void kernel_launch(void* const* d_in, const int* in_sizes, int n_in,
                              void* d_out, int out_size, void* d_ws, size_t ws_size,
                              hipStream_t stream) {
    const float* X      = (const float*)d_in[0];
    const int*   H_rows = (const int*)d_in[1];
    const int*   H_cols = (const int*)d_in[2];
    const float* H_vals = (const float*)d_in[3];
    const float* W1     = (const float*)d_in[4];
    const float* b1     = (const float*)d_in[5];
    const float* W2     = (const float*)d_in[6];
    const float* b2     = (const float*)d_in[7];
    float* out = (float*)d_out;

    const int E = in_sizes[1];
    const size_t mat_bytes = (size_t)NNODES * DIM * sizeof(float);

    float* Y = (float*)d_ws;                        // GEMM output (reused both layers)
    float* h = (float*)((char*)d_ws + mat_bytes);   // SpMM1 accumulator

    const int gemm_blocks = (NNODES + 15) / 16;
    const long long spmm_threads = (long long)E * DIM;
    const int spmm_blocks = (int)((spmm_threads + 255) / 256);

    // Zero accumulators up front (d_ws / d_out are poisoned 0xAA before each call).
    hipMemsetAsync(h, 0, mat_bytes, stream);
    hipMemsetAsync(out, 0, mat_bytes, stream);

    // Layer 1: Y = X @ W1 + b1 ; h = H @ Y
    gemm_bias<false><<<gemm_blocks, 256, 0, stream>>>(X, W1, b1, Y, NNODES);
    spmm_atomic<<<spmm_blocks, 256, 0, stream>>>(H_rows, H_cols, H_vals, Y, h, E);

    // Layer 2: Y = relu(h) @ W2 + b2 ; out = H @ Y
    gemm_bias<true><<<gemm_blocks, 256, 0, stream>>>(h, W2, b2, Y, NNODES);
    spmm_atomic<<<spmm_blocks, 256, 0, stream>>>(H_rows, H_cols, H_vals, Y, out, E);
}

// Round 2
// 677.089 us; speedup vs baseline: 2.4099x; 2.4099x over previous
//
#include <hip/hip_runtime.h>

#define NNODES 100000
#define DIM 128
#define SCAN_BLK 256

// ---------------- Dense GEMM: Y = act(X) @ W + b ----------------
template <bool RELU_IN>
__global__ __launch_bounds__(256) void gemm_bias(const float* __restrict__ X,
                                                 const float* __restrict__ W,
                                                 const float* __restrict__ b,
                                                 float* __restrict__ Y, int n) {
    __shared__ float xs[16][DIM];
    const int row0 = blockIdx.x * 16;
    const int t = threadIdx.x;

    for (int i = t; i < 16 * DIM; i += 256) {
        const int r = i >> 7, k = i & 127;
        const int rr = row0 + r;
        float v = (rr < n) ? X[(size_t)rr * DIM + k] : 0.f;
        if (RELU_IN) v = fmaxf(v, 0.f);
        xs[r][k] = v;
    }
    __syncthreads();

    const int c = t & 127;
    const int rbase = (t >> 7) * 8;
    float acc[8];
    const float bias = b[c];
#pragma unroll
    for (int r = 0; r < 8; ++r) acc[r] = bias;

    for (int k = 0; k < DIM; ++k) {
        const float wv = W[k * DIM + c];
#pragma unroll
        for (int r = 0; r < 8; ++r) acc[r] += xs[rbase + r][k] * wv;
    }

#pragma unroll
    for (int r = 0; r < 8; ++r) {
        const int rr = row0 + rbase + r;
        if (rr < n) Y[(size_t)rr * DIM + c] = acc[r];
    }
}

// ---------------- CSR build ----------------
__global__ __launch_bounds__(256) void hist_rows(const int* __restrict__ rows,
                                                 int* __restrict__ counts, int nnz) {
    const int e = blockIdx.x * blockDim.x + threadIdx.x;
    if (e < nnz) atomicAdd(&counts[rows[e]], 1);
}

// Exclusive scan of `counts` in 256-element chunks; per-chunk totals to `partials`.
__global__ __launch_bounds__(SCAN_BLK) void scan_chunks(const int* __restrict__ counts,
                                                        int* __restrict__ excl,
                                                        int* __restrict__ partials, int n) {
    __shared__ int s[SCAN_BLK];
    const int t = threadIdx.x;
    const int i = blockIdx.x * SCAN_BLK + t;
    const int v = (i < n) ? counts[i] : 0;
    s[t] = v;
    __syncthreads();
    for (int off = 1; off < SCAN_BLK; off <<= 1) {
        int x = (t >= off) ? s[t - off] : 0;
        __syncthreads();
        s[t] += x;
        __syncthreads();
    }
    if (i < n) excl[i] = s[t] - v;
    if (t == SCAN_BLK - 1) partials[blockIdx.x] = s[t];
}

// Single-block exclusive scan of the chunk totals (np <= 512).
__global__ __launch_bounds__(512) void scan_partials(int* __restrict__ partials, int np) {
    __shared__ int s[512];
    const int t = threadIdx.x;
    const int v = (t < np) ? partials[t] : 0;
    s[t] = v;
    __syncthreads();
    for (int off = 1; off < 512; off <<= 1) {
        int x = (t >= off) ? s[t - off] : 0;
        __syncthreads();
        s[t] += x;
        __syncthreads();
    }
    if (t < np) partials[t] = s[t] - v;
}

__global__ __launch_bounds__(256) void add_offsets(int* __restrict__ excl,
                                                   const int* __restrict__ partials,
                                                   int* __restrict__ cursor, int n) {
    const int i = blockIdx.x * blockDim.x + threadIdx.x;
    if (i < n) {
        const int rp = excl[i] + partials[i / SCAN_BLK];
        excl[i] = rp;
        cursor[i] = rp;
    }
}

__global__ __launch_bounds__(256) void scatter_edges(const int* __restrict__ rows,
                                                     const int* __restrict__ cols,
                                                     const float* __restrict__ vals,
                                                     int* __restrict__ cursor,
                                                     int* __restrict__ ccols,
                                                     float* __restrict__ cvals, int nnz) {
    const int e = blockIdx.x * blockDim.x + threadIdx.x;
    if (e < nnz) {
        const int pos = atomicAdd(&cursor[rows[e]], 1);
        ccols[pos] = cols[e];
        cvals[pos] = vals[e];
    }
}

// ---------------- Row-parallel SpMM: out[r] = sum_j v_j * X[c_j] ----------------
// 32 threads per row, float4 per lane (32*16B = 512B = one row).
__global__ __launch_bounds__(256) void spmm_csr(const int* __restrict__ row_ptr,
                                                const int* __restrict__ counts,
                                                const int* __restrict__ ccols,
                                                const float* __restrict__ cvals,
                                                const float* __restrict__ X,
                                                float* __restrict__ out, int n) {
    const int gid = blockIdx.x * blockDim.x + threadIdx.x;
    const int r = gid >> 5;
    const int lane = gid & 31;
    if (r >= n) return;
    const int start = row_ptr[r];
    const int cnt = counts[r];
    const float4* __restrict__ X4 = (const float4*)X;
    float4 acc = make_float4(0.f, 0.f, 0.f, 0.f);
    for (int j = 0; j < cnt; ++j) {
        const int c = ccols[start + j];       // wave-uniform broadcast load
        const float v = cvals[start + j];
        const float4 x = X4[(size_t)c * 32 + lane];
        acc.x += v * x.x;
        acc.y += v * x.y;
        acc.z += v * x.z;
        acc.w += v * x.w;
    }
    ((float4*)out)[(size_t)r * 32 + lane] = acc;
}

// ---------------- Fallback (round-1 path) ----------------
__global__ __launch_bounds__(256) void spmm_atomic(const int* __restrict__ rows,
                                                   const int* __restrict__ cols,
                                                   const float* __restrict__ vals,
                                                   const float* __restrict__ X,
                                                   float* __restrict__ out, int nnz) {
    const long long idx = (long long)blockIdx.x * blockDim.x + threadIdx.x;
    const int e = (int)(idx >> 7);
    const int f = (int)(idx & 127);
    if (e >= nnz) return;
    atomicAdd(&out[(size_t)rows[e] * DIM + f], vals[e] * X[(size_t)cols[e] * DIM + f]);
}

extern "C" void kernel_launch(void* const* d_in, const int* in_sizes, int n_in,
                              void* d_out, int out_size, void* d_ws, size_t ws_size,
                              hipStream_t stream) {
    const float* X      = (const float*)d_in[0];
    const int*   H_rows = (const int*)d_in[1];
    const int*   H_cols = (const int*)d_in[2];
    const float* H_vals = (const float*)d_in[3];
    const float* W1     = (const float*)d_in[4];
    const float* b1     = (const float*)d_in[5];
    const float* W2     = (const float*)d_in[6];
    const float* b2     = (const float*)d_in[7];
    float* out = (float*)d_out;

    const int E = in_sizes[1];
    const int N = NNODES;
    const size_t mat_bytes = (size_t)N * DIM * sizeof(float);

    const int gemm_blocks = (N + 15) / 16;
    const int eblocks = (E + 255) / 256;
    const int nblocks = (N + 255) / 256;
    const int nchunks = (N + SCAN_BLK - 1) / SCAN_BLK;  // 391

    // Workspace layout
    char* p = (char*)d_ws;
    float* Y       = (float*)p;               p += mat_bytes;            // 51.2 MB
    float* h       = (float*)p;               p += mat_bytes;            // 51.2 MB
    int*   ccols   = (int*)p;                 p += (size_t)E * 4;        // 6.4 MB
    float* cvals   = (float*)p;               p += (size_t)E * 4;        // 6.4 MB
    int*   counts  = (int*)p;                 p += (size_t)N * 4;        // 0.4 MB
    int*   row_ptr = (int*)p;                 p += (size_t)N * 4;        // 0.4 MB
    int*   cursor  = (int*)p;                 p += (size_t)N * 4;        // 0.4 MB
    int*   partials= (int*)p;                 p += 4096;
    const size_t need = (size_t)(p - (char*)d_ws);

    if (ws_size >= need) {
        // ---- CSR build (once, reused by both SpMMs) ----
        hipMemsetAsync(counts, 0, (size_t)N * 4, stream);
        hist_rows<<<eblocks, 256, 0, stream>>>(H_rows, counts, E);
        scan_chunks<<<nchunks, SCAN_BLK, 0, stream>>>(counts, row_ptr, partials, N);
        scan_partials<<<1, 512, 0, stream>>>(partials, nchunks);
        add_offsets<<<nblocks, 256, 0, stream>>>(row_ptr, partials, cursor, N);
        scatter_edges<<<eblocks, 256, 0, stream>>>(H_rows, H_cols, H_vals, cursor,
                                                   ccols, cvals, E);

        const int spmm_blocks = (N * 32 + 255) / 256;
        // Layer 1
        gemm_bias<false><<<gemm_blocks, 256, 0, stream>>>(X, W1, b1, Y, N);
        spmm_csr<<<spmm_blocks, 256, 0, stream>>>(row_ptr, counts, ccols, cvals, Y, h, N);
        // Layer 2
        gemm_bias<true><<<gemm_blocks, 256, 0, stream>>>(h, W2, b2, Y, N);
        spmm_csr<<<spmm_blocks, 256, 0, stream>>>(row_ptr, counts, ccols, cvals, Y, out, N);
    } else {
        // Fallback: round-1 atomic path (needs only 2*mat_bytes)
        const long long spmm_threads = (long long)E * DIM;
        const int spmm_blocks = (int)((spmm_threads + 255) / 256);
        hipMemsetAsync(h, 0, mat_bytes, stream);
        hipMemsetAsync(out, 0, mat_bytes, stream);
        gemm_bias<false><<<gemm_blocks, 256, 0, stream>>>(X, W1, b1, Y, N);
        spmm_atomic<<<spmm_blocks, 256, 0, stream>>>(H_rows, H_cols, H_vals, Y, h, E);
        gemm_bias<true><<<gemm_blocks, 256, 0, stream>>>(h, W2, b2, Y, N);
        spmm_atomic<<<spmm_blocks, 256, 0, stream>>>(H_rows, H_cols, H_vals, Y, out, E);
    }
}

// Round 3
// 636.086 us; speedup vs baseline: 2.5652x; 1.0645x over previous
//
#include <hip/hip_runtime.h>

#define NNODES 100000
#define DIM 128
#define SCAN_BLK 256

__device__ __forceinline__ float f4c(const float4& v, int q) {
    switch (q) { case 0: return v.x; case 1: return v.y; case 2: return v.z; }
    return v.w;
}

// ---------------- Dense GEMM: Y = act(X) @ W + b ----------------
// 128x128 block tile, 256 threads (16x16), 8x8 per-thread register tile with
// quadrant split (rows ty*4+i and 64+ty*4+i; cols tx*4+j and 64+tx*4+j) so all
// LDS b128 reads are <=2-way bank-aliased (free). K staged in 4 phases of 32.
// LDS: A tile [128][36] (9-granule row stride -> (9*row+k4)%8 spreads groups),
//      B tile [32][128]. Total 34816 B -> 2 blocks/CU.
template <bool RELU_IN>
__global__ __launch_bounds__(256, 2) void gemm_tile(const float* __restrict__ A,
                                                    const float* __restrict__ W,
                                                    const float* __restrict__ bias,
                                                    float* __restrict__ Y, int n) {
    __shared__ float as[128 * 36];
    __shared__ float bs[32 * 128];
    const int t = threadIdx.x;
    const int tx = t & 15, ty = t >> 4;
    const int row0 = blockIdx.x * 128;
    const int r_lo = ty * 4;
    const int c_lo = tx * 4;

    float acc[8][8];
    {
        const float4 bv0 = *(const float4*)&bias[c_lo];
        const float4 bv1 = *(const float4*)&bias[64 + c_lo];
#pragma unroll
        for (int i = 0; i < 8; ++i) {
            acc[i][0] = bv0.x; acc[i][1] = bv0.y; acc[i][2] = bv0.z; acc[i][3] = bv0.w;
            acc[i][4] = bv1.x; acc[i][5] = bv1.y; acc[i][6] = bv1.z; acc[i][7] = bv1.w;
        }
    }

    const float4* A4 = (const float4*)A;
    const float4* W4 = (const float4*)W;

    for (int kp = 0; kp < 4; ++kp) {
        // Stage A phase tile: 128 rows x 8 float4 (k-chunk), coalesced per row.
#pragma unroll
        for (int j = 0; j < 4; ++j) {
            const int l = t + j * 256;
            const int row = l >> 3, k4 = l & 7;
            const int rr = row0 + row;
            float4 v = make_float4(0.f, 0.f, 0.f, 0.f);
            if (rr < n) v = A4[(size_t)rr * 32 + kp * 8 + k4];
            if (RELU_IN) {
                v.x = fmaxf(v.x, 0.f); v.y = fmaxf(v.y, 0.f);
                v.z = fmaxf(v.z, 0.f); v.w = fmaxf(v.w, 0.f);
            }
            *(float4*)&as[row * 36 + k4 * 4] = v;
        }
        // Stage B phase tile: 32 k-rows x 32 float4, perfectly coalesced.
#pragma unroll
        for (int j = 0; j < 4; ++j) {
            const int l = t + j * 256;
            const int k = l >> 5, c4 = l & 31;
            *(float4*)&bs[k * 128 + c4 * 4] = W4[(size_t)(kp * 32 + k) * 32 + c4];
        }
        __syncthreads();

#pragma unroll 2
        for (int kk = 0; kk < 32; kk += 4) {
            float4 a[8], b0[4], b1[4];
#pragma unroll
            for (int i = 0; i < 4; ++i) {
                a[i]     = *(const float4*)&as[(r_lo + i) * 36 + kk];
                a[4 + i] = *(const float4*)&as[(64 + r_lo + i) * 36 + kk];
            }
#pragma unroll
            for (int q = 0; q < 4; ++q) {
                b0[q] = *(const float4*)&bs[(kk + q) * 128 + c_lo];
                b1[q] = *(const float4*)&bs[(kk + q) * 128 + 64 + c_lo];
            }
#pragma unroll
            for (int q = 0; q < 4; ++q) {
#pragma unroll
                for (int i = 0; i < 8; ++i) {
                    const float av = f4c(a[i], q);
                    acc[i][0] = fmaf(av, b0[q].x, acc[i][0]);
                    acc[i][1] = fmaf(av, b0[q].y, acc[i][1]);
                    acc[i][2] = fmaf(av, b0[q].z, acc[i][2]);
                    acc[i][3] = fmaf(av, b0[q].w, acc[i][3]);
                    acc[i][4] = fmaf(av, b1[q].x, acc[i][4]);
                    acc[i][5] = fmaf(av, b1[q].y, acc[i][5]);
                    acc[i][6] = fmaf(av, b1[q].z, acc[i][6]);
                    acc[i][7] = fmaf(av, b1[q].w, acc[i][7]);
                }
            }
        }
        __syncthreads();
    }

#pragma unroll
    for (int i = 0; i < 8; ++i) {
        const int lr = (i < 4) ? (r_lo + i) : (64 + r_lo + i - 4);
        const int rr = row0 + lr;
        if (rr < n) {
            float4 o0 = make_float4(acc[i][0], acc[i][1], acc[i][2], acc[i][3]);
            float4 o1 = make_float4(acc[i][4], acc[i][5], acc[i][6], acc[i][7]);
            *(float4*)&Y[(size_t)rr * DIM + c_lo] = o0;
            *(float4*)&Y[(size_t)rr * DIM + 64 + c_lo] = o1;
        }
    }
}

// ---------------- CSR build ----------------
__global__ __launch_bounds__(256) void hist_rows(const int* __restrict__ rows,
                                                 int* __restrict__ counts, int nnz) {
    const int e = blockIdx.x * blockDim.x + threadIdx.x;
    if (e < nnz) atomicAdd(&counts[rows[e]], 1);
}

__global__ __launch_bounds__(SCAN_BLK) void scan_chunks(const int* __restrict__ counts,
                                                        int* __restrict__ excl,
                                                        int* __restrict__ partials, int n) {
    __shared__ int s[SCAN_BLK];
    const int t = threadIdx.x;
    const int i = blockIdx.x * SCAN_BLK + t;
    const int v = (i < n) ? counts[i] : 0;
    s[t] = v;
    __syncthreads();
    for (int off = 1; off < SCAN_BLK; off <<= 1) {
        int x = (t >= off) ? s[t - off] : 0;
        __syncthreads();
        s[t] += x;
        __syncthreads();
    }
    if (i < n) excl[i] = s[t] - v;
    if (t == SCAN_BLK - 1) partials[blockIdx.x] = s[t];
}

__global__ __launch_bounds__(512) void scan_partials(int* __restrict__ partials, int np) {
    __shared__ int s[512];
    const int t = threadIdx.x;
    const int v = (t < np) ? partials[t] : 0;
    s[t] = v;
    __syncthreads();
    for (int off = 1; off < 512; off <<= 1) {
        int x = (t >= off) ? s[t - off] : 0;
        __syncthreads();
        s[t] += x;
        __syncthreads();
    }
    if (t < np) partials[t] = s[t] - v;
}

__global__ __launch_bounds__(256) void add_offsets(int* __restrict__ excl,
                                                   const int* __restrict__ partials,
                                                   int* __restrict__ cursor, int n) {
    const int i = blockIdx.x * blockDim.x + threadIdx.x;
    if (i < n) {
        const int rp = excl[i] + partials[i / SCAN_BLK];
        excl[i] = rp;
        cursor[i] = rp;
    }
}

__global__ __launch_bounds__(256) void scatter_edges(const int* __restrict__ rows,
                                                     const int* __restrict__ cols,
                                                     const float* __restrict__ vals,
                                                     int* __restrict__ cursor,
                                                     int* __restrict__ ccols,
                                                     float* __restrict__ cvals, int nnz) {
    const int e = blockIdx.x * blockDim.x + threadIdx.x;
    if (e < nnz) {
        const int pos = atomicAdd(&cursor[rows[e]], 1);
        ccols[pos] = cols[e];
        cvals[pos] = vals[e];
    }
}

// ---------------- Row-parallel SpMM: out[r] = sum_j v_j * X[c_j] ----------------
// 16 lanes per row (4 rows/wave), 2 float4 per lane, j-loop unrolled 4 deep:
// up to 32 independent gathers in flight per wave (latency hiding).
__global__ __launch_bounds__(256) void spmm_csr(const int* __restrict__ row_ptr,
                                                const int* __restrict__ counts,
                                                const int* __restrict__ ccols,
                                                const float* __restrict__ cvals,
                                                const float* __restrict__ X,
                                                float* __restrict__ out, int n) {
    const int gid = blockIdx.x * blockDim.x + threadIdx.x;
    const int r = gid >> 4;
    const int lane = gid & 15;
    if (r >= n) return;
    const int start = row_ptr[r];
    const int cnt = counts[r];
    const float4* __restrict__ X4 = (const float4*)X;

    float4 acc0 = make_float4(0.f, 0.f, 0.f, 0.f);
    float4 acc1 = make_float4(0.f, 0.f, 0.f, 0.f);

    int j = 0;
    for (; j + 4 <= cnt; j += 4) {
        const int b = start + j;
        const int c0 = ccols[b + 0], c1 = ccols[b + 1], c2 = ccols[b + 2], c3 = ccols[b + 3];
        const float v0 = cvals[b + 0], v1 = cvals[b + 1], v2 = cvals[b + 2], v3 = cvals[b + 3];
        const float4 xa0 = X4[(size_t)c0 * 32 + lane],      xb0 = X4[(size_t)c0 * 32 + 16 + lane];
        const float4 xa1 = X4[(size_t)c1 * 32 + lane],      xb1 = X4[(size_t)c1 * 32 + 16 + lane];
        const float4 xa2 = X4[(size_t)c2 * 32 + lane],      xb2 = X4[(size_t)c2 * 32 + 16 + lane];
        const float4 xa3 = X4[(size_t)c3 * 32 + lane],      xb3 = X4[(size_t)c3 * 32 + 16 + lane];
        acc0.x += v0 * xa0.x + v1 * xa1.x + v2 * xa2.x + v3 * xa3.x;
        acc0.y += v0 * xa0.y + v1 * xa1.y + v2 * xa2.y + v3 * xa3.y;
        acc0.z += v0 * xa0.z + v1 * xa1.z + v2 * xa2.z + v3 * xa3.z;
        acc0.w += v0 * xa0.w + v1 * xa1.w + v2 * xa2.w + v3 * xa3.w;
        acc1.x += v0 * xb0.x + v1 * xb1.x + v2 * xb2.x + v3 * xb3.x;
        acc1.y += v0 * xb0.y + v1 * xb1.y + v2 * xb2.y + v3 * xb3.y;
        acc1.z += v0 * xb0.z + v1 * xb1.z + v2 * xb2.z + v3 * xb3.z;
        acc1.w += v0 * xb0.w + v1 * xb1.w + v2 * xb2.w + v3 * xb3.w;
    }
    for (; j < cnt; ++j) {
        const int c = ccols[start + j];
        const float v = cvals[start + j];
        const float4 xa = X4[(size_t)c * 32 + lane];
        const float4 xb = X4[(size_t)c * 32 + 16 + lane];
        acc0.x += v * xa.x; acc0.y += v * xa.y; acc0.z += v * xa.z; acc0.w += v * xa.w;
        acc1.x += v * xb.x; acc1.y += v * xb.y; acc1.z += v * xb.z; acc1.w += v * xb.w;
    }
    ((float4*)out)[(size_t)r * 32 + lane] = acc0;
    ((float4*)out)[(size_t)r * 32 + 16 + lane] = acc1;
}

extern "C" void kernel_launch(void* const* d_in, const int* in_sizes, int n_in,
                              void* d_out, int out_size, void* d_ws, size_t ws_size,
                              hipStream_t stream) {
    const float* X      = (const float*)d_in[0];
    const int*   H_rows = (const int*)d_in[1];
    const int*   H_cols = (const int*)d_in[2];
    const float* H_vals = (const float*)d_in[3];
    const float* W1     = (const float*)d_in[4];
    const float* b1     = (const float*)d_in[5];
    const float* W2     = (const float*)d_in[6];
    const float* b2     = (const float*)d_in[7];
    float* out = (float*)d_out;

    const int E = in_sizes[1];
    const int N = NNODES;
    const size_t mat_bytes = (size_t)N * DIM * sizeof(float);

    const int gemm_blocks = (N + 127) / 128;
    const int eblocks = (E + 255) / 256;
    const int nblocks = (N + 255) / 256;
    const int nchunks = (N + SCAN_BLK - 1) / SCAN_BLK;

    // Workspace layout
    char* p = (char*)d_ws;
    float* Y        = (float*)p;  p += mat_bytes;
    float* h        = (float*)p;  p += mat_bytes;
    int*   ccols    = (int*)p;    p += (size_t)E * 4;
    float* cvals    = (float*)p;  p += (size_t)E * 4;
    int*   counts   = (int*)p;    p += (size_t)N * 4;
    int*   row_ptr  = (int*)p;    p += (size_t)N * 4;
    int*   cursor   = (int*)p;    p += (size_t)N * 4;
    int*   partials = (int*)p;    p += 4096;

    // ---- CSR build (reused by both SpMMs) ----
    hipMemsetAsync(counts, 0, (size_t)N * 4, stream);
    hist_rows<<<eblocks, 256, 0, stream>>>(H_rows, counts, E);
    scan_chunks<<<nchunks, SCAN_BLK, 0, stream>>>(counts, row_ptr, partials, N);
    scan_partials<<<1, 512, 0, stream>>>(partials, nchunks);
    add_offsets<<<nblocks, 256, 0, stream>>>(row_ptr, partials, cursor, N);
    scatter_edges<<<eblocks, 256, 0, stream>>>(H_rows, H_cols, H_vals, cursor,
                                               ccols, cvals, E);

    const int spmm_blocks = (N * 16 + 255) / 256;
    // Layer 1: Y = X @ W1 + b1 ; h = H @ Y
    gemm_tile<false><<<gemm_blocks, 256, 0, stream>>>(X, W1, b1, Y, N);
    spmm_csr<<<spmm_blocks, 256, 0, stream>>>(row_ptr, counts, ccols, cvals, Y, h, N);
    // Layer 2: Y = relu(h) @ W2 + b2 ; out = H @ Y
    gemm_tile<true><<<gemm_blocks, 256, 0, stream>>>(h, W2, b2, Y, N);
    spmm_csr<<<spmm_blocks, 256, 0, stream>>>(row_ptr, counts, ccols, cvals, Y, out, N);
}

// Round 4
// 519.855 us; speedup vs baseline: 3.1387x; 1.2236x over previous
//
#include <hip/hip_runtime.h>

#define NNODES 100000
#define DIM 128
#define SCAN_BLK 256

__device__ __forceinline__ float f4c(const float4& v, int q) {
    switch (q) { case 0: return v.x; case 1: return v.y; case 2: return v.z; }
    return v.w;
}

__device__ __forceinline__ unsigned int pack_bf16x2(float lo, float hi) {
    unsigned int ul = __float_as_uint(lo);
    unsigned int uh = __float_as_uint(hi);
    ul = (ul + 0x7fffu + ((ul >> 16) & 1u)) >> 16;   // RNE
    uh = (uh + 0x7fffu + ((uh >> 16) & 1u)) & 0xffff0000u;
    return uh | ul;
}

__device__ __forceinline__ void unpack_bf16x8(uint4 v, float* f) {
    f[0] = __uint_as_float(v.x << 16); f[1] = __uint_as_float(v.x & 0xffff0000u);
    f[2] = __uint_as_float(v.y << 16); f[3] = __uint_as_float(v.y & 0xffff0000u);
    f[4] = __uint_as_float(v.z << 16); f[5] = __uint_as_float(v.z & 0xffff0000u);
    f[6] = __uint_as_float(v.w << 16); f[7] = __uint_as_float(v.w & 0xffff0000u);
}

// ---------------- Dense GEMM: Yb(bf16) = A @ W + b ----------------
// 128x128 tile, 256 threads, 8x8 register tile, quadrant split (<=2-way LDS
// bank aliasing = free). K in 4 phases of 32. A input fp32 or bf16.
template <bool IN_BF16>
__global__ __launch_bounds__(256, 2) void gemm_tile(const void* __restrict__ Ain,
                                                    const float* __restrict__ W,
                                                    const float* __restrict__ bias,
                                                    unsigned short* __restrict__ Yb, int n) {
    __shared__ float as[128 * 36];
    __shared__ float bs[32 * 128];
    const int t = threadIdx.x;
    const int tx = t & 15, ty = t >> 4;
    const int row0 = blockIdx.x * 128;
    const int r_lo = ty * 4;
    const int c_lo = tx * 4;

    float acc[8][8];
    {
        const float4 bv0 = *(const float4*)&bias[c_lo];
        const float4 bv1 = *(const float4*)&bias[64 + c_lo];
#pragma unroll
        for (int i = 0; i < 8; ++i) {
            acc[i][0] = bv0.x; acc[i][1] = bv0.y; acc[i][2] = bv0.z; acc[i][3] = bv0.w;
            acc[i][4] = bv1.x; acc[i][5] = bv1.y; acc[i][6] = bv1.z; acc[i][7] = bv1.w;
        }
    }

    const float4* W4 = (const float4*)W;

    for (int kp = 0; kp < 4; ++kp) {
        // Stage A phase tile (128 rows x 32 k) into LDS as fp32.
        if (IN_BF16) {
            const uint4* A16 = (const uint4*)Ain;  // 16 chunks of 8 bf16 per row
#pragma unroll
            for (int j = 0; j < 2; ++j) {
                const int l = t + j * 256;          // 0..511
                const int row = l >> 2, ch = l & 3; // chunk = 8 feats
                const int rr = row0 + row;
                uint4 v = make_uint4(0u, 0u, 0u, 0u);
                if (rr < n) v = A16[(size_t)rr * 16 + kp * 4 + ch];
                float f[8];
                unpack_bf16x8(v, f);
                float* dst = &as[row * 36 + ch * 8];
                *(float4*)&dst[0] = make_float4(f[0], f[1], f[2], f[3]);
                *(float4*)&dst[4] = make_float4(f[4], f[5], f[6], f[7]);
            }
        } else {
            const float4* A4 = (const float4*)Ain;
#pragma unroll
            for (int j = 0; j < 4; ++j) {
                const int l = t + j * 256;
                const int row = l >> 3, k4 = l & 7;
                const int rr = row0 + row;
                float4 v = make_float4(0.f, 0.f, 0.f, 0.f);
                if (rr < n) v = A4[(size_t)rr * 32 + kp * 8 + k4];
                *(float4*)&as[row * 36 + k4 * 4] = v;
            }
        }
        // Stage B phase tile (32 k x 128 c), coalesced.
#pragma unroll
        for (int j = 0; j < 4; ++j) {
            const int l = t + j * 256;
            const int k = l >> 5, c4 = l & 31;
            *(float4*)&bs[k * 128 + c4 * 4] = W4[(size_t)(kp * 32 + k) * 32 + c4];
        }
        __syncthreads();

#pragma unroll 2
        for (int kk = 0; kk < 32; kk += 4) {
            float4 a[8], b0[4], b1[4];
#pragma unroll
            for (int i = 0; i < 4; ++i) {
                a[i]     = *(const float4*)&as[(r_lo + i) * 36 + kk];
                a[4 + i] = *(const float4*)&as[(64 + r_lo + i) * 36 + kk];
            }
#pragma unroll
            for (int q = 0; q < 4; ++q) {
                b0[q] = *(const float4*)&bs[(kk + q) * 128 + c_lo];
                b1[q] = *(const float4*)&bs[(kk + q) * 128 + 64 + c_lo];
            }
#pragma unroll
            for (int q = 0; q < 4; ++q) {
#pragma unroll
                for (int i = 0; i < 8; ++i) {
                    const float av = f4c(a[i], q);
                    acc[i][0] = fmaf(av, b0[q].x, acc[i][0]);
                    acc[i][1] = fmaf(av, b0[q].y, acc[i][1]);
                    acc[i][2] = fmaf(av, b0[q].z, acc[i][2]);
                    acc[i][3] = fmaf(av, b0[q].w, acc[i][3]);
                    acc[i][4] = fmaf(av, b1[q].x, acc[i][4]);
                    acc[i][5] = fmaf(av, b1[q].y, acc[i][5]);
                    acc[i][6] = fmaf(av, b1[q].z, acc[i][6]);
                    acc[i][7] = fmaf(av, b1[q].w, acc[i][7]);
                }
            }
        }
        __syncthreads();
    }

#pragma unroll
    for (int i = 0; i < 8; ++i) {
        const int lr = (i < 4) ? (r_lo + i) : (64 + r_lo + i - 4);
        const int rr = row0 + lr;
        if (rr < n) {
            uint2 lo = make_uint2(pack_bf16x2(acc[i][0], acc[i][1]),
                                  pack_bf16x2(acc[i][2], acc[i][3]));
            uint2 hi = make_uint2(pack_bf16x2(acc[i][4], acc[i][5]),
                                  pack_bf16x2(acc[i][6], acc[i][7]));
            *(uint2*)&Yb[(size_t)rr * DIM + c_lo] = lo;
            *(uint2*)&Yb[(size_t)rr * DIM + 64 + c_lo] = hi;
        }
    }
}

// ---------------- CSR build ----------------
__global__ __launch_bounds__(256) void hist_rows(const int* __restrict__ rows,
                                                 int* __restrict__ counts, int nnz) {
    const int e = blockIdx.x * blockDim.x + threadIdx.x;
    if (e < nnz) atomicAdd(&counts[rows[e]], 1);
}

__global__ __launch_bounds__(SCAN_BLK) void scan_chunks(const int* __restrict__ counts,
                                                        int* __restrict__ excl,
                                                        int* __restrict__ partials, int n) {
    __shared__ int s[SCAN_BLK];
    const int t = threadIdx.x;
    const int i = blockIdx.x * SCAN_BLK + t;
    const int v = (i < n) ? counts[i] : 0;
    s[t] = v;
    __syncthreads();
    for (int off = 1; off < SCAN_BLK; off <<= 1) {
        int x = (t >= off) ? s[t - off] : 0;
        __syncthreads();
        s[t] += x;
        __syncthreads();
    }
    if (i < n) excl[i] = s[t] - v;
    if (t == SCAN_BLK - 1) partials[blockIdx.x] = s[t];
}

__global__ __launch_bounds__(512) void scan_partials(int* __restrict__ partials, int np) {
    __shared__ int s[512];
    const int t = threadIdx.x;
    const int v = (t < np) ? partials[t] : 0;
    s[t] = v;
    __syncthreads();
    for (int off = 1; off < 512; off <<= 1) {
        int x = (t >= off) ? s[t - off] : 0;
        __syncthreads();
        s[t] += x;
        __syncthreads();
    }
    if (t < np) partials[t] = s[t] - v;
}

__global__ __launch_bounds__(256) void add_offsets(int* __restrict__ excl,
                                                   const int* __restrict__ partials,
                                                   int* __restrict__ cursor, int n) {
    const int i = blockIdx.x * blockDim.x + threadIdx.x;
    if (i < n) {
        const int rp = excl[i] + partials[i / SCAN_BLK];
        excl[i] = rp;
        cursor[i] = rp;
    }
}

__global__ __launch_bounds__(256) void scatter_edges(const int* __restrict__ rows,
                                                     const int* __restrict__ cols,
                                                     const float* __restrict__ vals,
                                                     int* __restrict__ cursor,
                                                     int2* __restrict__ epack, int nnz) {
    const int e = blockIdx.x * blockDim.x + threadIdx.x;
    if (e < nnz) {
        const int pos = atomicAdd(&cursor[rows[e]], 1);
        epack[pos] = make_int2(cols[e], __float_as_int(vals[e]));
    }
}

// ---------------- SpMM: out[r] = sum_j v_j * Xb[c_j]  (bf16 gather) ----------------
// 16 lanes/row; lane loads one uint4 (8 bf16 feats) per edge. fp32 accumulate.
template <bool RELU_OUT, bool OUT_BF16>
__global__ __launch_bounds__(256) void spmm_csr(const int* __restrict__ row_ptr,
                                                const int* __restrict__ counts,
                                                const int2* __restrict__ epack,
                                                const unsigned short* __restrict__ Xb,
                                                void* __restrict__ out, int n) {
    const int gid = blockIdx.x * blockDim.x + threadIdx.x;
    const int r = gid >> 4;
    const int lane = gid & 15;
    if (r >= n) return;
    const int start = row_ptr[r];
    const int cnt = counts[r];
    const uint4* __restrict__ X16 = (const uint4*)Xb;  // 16 chunks per row
    const int2* __restrict__ ep = epack + start;

    float acc[8];
#pragma unroll
    for (int k = 0; k < 8; ++k) acc[k] = 0.f;

    int j = 0;
    for (; j + 4 <= cnt; j += 4) {
        const int2 e0 = ep[j], e1 = ep[j + 1], e2 = ep[j + 2], e3 = ep[j + 3];
        const uint4 x0 = X16[(size_t)e0.x * 16 + lane];
        const uint4 x1 = X16[(size_t)e1.x * 16 + lane];
        const uint4 x2 = X16[(size_t)e2.x * 16 + lane];
        const uint4 x3 = X16[(size_t)e3.x * 16 + lane];
        const float v0 = __int_as_float(e0.y), v1 = __int_as_float(e1.y);
        const float v2 = __int_as_float(e2.y), v3 = __int_as_float(e3.y);
        float f0[8], f1[8], f2[8], f3[8];
        unpack_bf16x8(x0, f0); unpack_bf16x8(x1, f1);
        unpack_bf16x8(x2, f2); unpack_bf16x8(x3, f3);
#pragma unroll
        for (int k = 0; k < 8; ++k)
            acc[k] += v0 * f0[k] + v1 * f1[k] + v2 * f2[k] + v3 * f3[k];
    }
    for (; j < cnt; ++j) {
        const int2 e = ep[j];
        const uint4 x = X16[(size_t)e.x * 16 + lane];
        const float v = __int_as_float(e.y);
        float f[8];
        unpack_bf16x8(x, f);
#pragma unroll
        for (int k = 0; k < 8; ++k) acc[k] += v * f[k];
    }

    if (RELU_OUT) {
#pragma unroll
        for (int k = 0; k < 8; ++k) acc[k] = fmaxf(acc[k], 0.f);
    }

    if (OUT_BF16) {
        uint4 pv = make_uint4(pack_bf16x2(acc[0], acc[1]), pack_bf16x2(acc[2], acc[3]),
                              pack_bf16x2(acc[4], acc[5]), pack_bf16x2(acc[6], acc[7]));
        ((uint4*)out)[(size_t)r * 16 + lane] = pv;
    } else {
        float* of = (float*)out;
        *(float4*)&of[(size_t)r * DIM + lane * 8]     = make_float4(acc[0], acc[1], acc[2], acc[3]);
        *(float4*)&of[(size_t)r * DIM + lane * 8 + 4] = make_float4(acc[4], acc[5], acc[6], acc[7]);
    }
}

extern "C" void kernel_launch(void* const* d_in, const int* in_sizes, int n_in,
                              void* d_out, int out_size, void* d_ws, size_t ws_size,
                              hipStream_t stream) {
    const float* X      = (const float*)d_in[0];
    const int*   H_rows = (const int*)d_in[1];
    const int*   H_cols = (const int*)d_in[2];
    const float* H_vals = (const float*)d_in[3];
    const float* W1     = (const float*)d_in[4];
    const float* b1     = (const float*)d_in[5];
    const float* W2     = (const float*)d_in[6];
    const float* b2     = (const float*)d_in[7];
    float* out = (float*)d_out;

    const int E = in_sizes[1];
    const int N = NNODES;
    const size_t bmat_bytes = (size_t)N * DIM * 2;   // bf16 matrix

    const int gemm_blocks = (N + 127) / 128;
    const int eblocks = (E + 255) / 256;
    const int nblocks = (N + 255) / 256;
    const int nchunks = (N + SCAN_BLK - 1) / SCAN_BLK;
    const int spmm_blocks = (N * 16 + 255) / 256;

    // Workspace layout
    char* p = (char*)d_ws;
    unsigned short* Yb  = (unsigned short*)p;  p += bmat_bytes;       // 25.6 MB (Y1, then Y2)
    unsigned short* hb  = (unsigned short*)p;  p += bmat_bytes;       // 25.6 MB (relu'd h)
    int2* epack         = (int2*)p;            p += (size_t)E * 8;    // 12.8 MB
    int*  counts        = (int*)p;             p += (size_t)N * 4;
    int*  row_ptr       = (int*)p;             p += (size_t)N * 4;
    int*  cursor        = (int*)p;             p += (size_t)N * 4;
    int*  partials      = (int*)p;             p += 4096;

    // ---- CSR build (reused by both SpMMs) ----
    hipMemsetAsync(counts, 0, (size_t)N * 4, stream);
    hist_rows<<<eblocks, 256, 0, stream>>>(H_rows, counts, E);
    scan_chunks<<<nchunks, SCAN_BLK, 0, stream>>>(counts, row_ptr, partials, N);
    scan_partials<<<1, 512, 0, stream>>>(partials, nchunks);
    add_offsets<<<nblocks, 256, 0, stream>>>(row_ptr, partials, cursor, N);
    scatter_edges<<<eblocks, 256, 0, stream>>>(H_rows, H_cols, H_vals, cursor, epack, E);

    // Layer 1: Yb = X @ W1 + b1 (bf16); hb = relu(H @ Yb) (bf16)
    gemm_tile<false><<<gemm_blocks, 256, 0, stream>>>(X, W1, b1, Yb, N);
    spmm_csr<true, true><<<spmm_blocks, 256, 0, stream>>>(row_ptr, counts, epack, Yb, hb, N);

    // Layer 2: Yb = hb @ W2 + b2 (bf16); out = H @ Yb (fp32)
    gemm_tile<true><<<gemm_blocks, 256, 0, stream>>>(hb, W2, b2, Yb, N);
    spmm_csr<false, false><<<spmm_blocks, 256, 0, stream>>>(row_ptr, counts, epack, Yb, out, N);
}